// Round 5
// baseline (4236.286 us; speedup 1.0000x reference)
//
#include <hip/hip_runtime.h>
#include <hip/hip_bf16.h>
#include <hip/hip_fp16.h>

typedef unsigned int uint32;
typedef _Float16 hf2 __attribute__((ext_vector_type(2)));

#define NT 1024

// ---------- helpers ----------
__device__ __forceinline__ float bfu(unsigned short v) { return __uint_as_float(((uint32)v) << 16); }
__device__ __forceinline__ unsigned short f2bf(float f) {
    uint32 u = __float_as_uint(f);
    u = (u + 0x7fffu + ((u >> 16) & 1u)) >> 16;
    return (unsigned short)u;
}
__device__ __forceinline__ uint32 pack_f16(float a, float b) {
    __half ha = __float2half_rn(a), hb = __float2half_rn(b);
    return (uint32)__half_as_ushort(ha) | ((uint32)__half_as_ushort(hb) << 16);
}
__device__ __forceinline__ float fexp2(float x) {
#if __has_builtin(__builtin_amdgcn_exp2f)
    return __builtin_amdgcn_exp2f(x);
#else
    return exp2f(x);
#endif
}
__device__ __forceinline__ float frcp(float x) {
#if __has_builtin(__builtin_amdgcn_rcpf)
    return __builtin_amdgcn_rcpf(x);
#else
    return __fdividef(1.f, x);
#endif
}
// tanh = 1 - 2/(1+e^{2x}); saturates correctly, no clamp needed.
__device__ __forceinline__ float fast_tanh(float x) {
    float e = fexp2(x * 2.8853900817779268f);  // 2*log2(e)
    return fmaf(-2.f, frcp(1.f + e), 1.f);
}
__device__ __forceinline__ float fast_sigmoid(float x) {
    return frcp(1.f + fexp2(-1.4426950408889634f * x));
}
// broadcast lane k's value (k wave-uniform) without DS traffic
__device__ __forceinline__ float rdlane(float v, int k) {
#if __has_builtin(__builtin_amdgcn_readlane)
    return __builtin_bit_cast(float, __builtin_amdgcn_readlane(__builtin_bit_cast(int, v), k));
#else
    return __shfl(v, k);
#endif
}
// 2-way f16 dot with f32 accumulate (v_dot2_f32_f16), guarded fallback
__device__ __forceinline__ float fdot2(uint32 w, uint32 v, float acc) {
#if __has_builtin(__builtin_amdgcn_fdot2)
    return __builtin_amdgcn_fdot2(__builtin_bit_cast(hf2, w), __builtin_bit_cast(hf2, v), acc, false);
#else
    __half2 wh = __builtin_bit_cast(__half2, w), vh = __builtin_bit_cast(__half2, v);
    float2 wf = __half22float2(wh), vf = __half22float2(vh);
    return fmaf(wf.y, vf.y, fmaf(wf.x, vf.x, acc));
#endif
}

// LDS flag ops (workgroup scope); fast-path check before first sleep
template <int S>
__device__ __forceinline__ void spin_ge(uint32* p, uint32 tgt) {
    if (__hip_atomic_load(p, __ATOMIC_ACQUIRE, __HIP_MEMORY_SCOPE_WORKGROUP) >= tgt) return;
    int guard = 0;
    do {
        __builtin_amdgcn_s_sleep(S);
        if (++guard > (1 << 22)) break;  // safety valve: wrong answer beats a hang
    } while (__hip_atomic_load(p, __ATOMIC_ACQUIRE, __HIP_MEMORY_SCOPE_WORKGROUP) < tgt);
}
__device__ __forceinline__ void st_flag(uint32* p, uint32 v) {
    __hip_atomic_store(p, v, __ATOMIC_RELEASE, __HIP_MEMORY_SCOPE_WORKGROUP);
}
__device__ __forceinline__ void add_flag(uint32* p, uint32 v) {
    __hip_atomic_fetch_add(p, v, __ATOMIC_RELEASE, __HIP_MEMORY_SCOPE_WORKGROUP);
}

// ---------- prep 1: f16-convert + re-layout weights (regions, proven) ----------
// We2: uint4[64][128]; [jq][s] = 4 half2 of We rows (hs reduction j in [0,512))
// Wc2 regions (uint32), [np][gate] layout (uint4 np*256+2*ol = gates 8ol..8ol+3):
//   [0, 65536):      region1, np in [0,64):  pack(W_ih[g][2np], [2np+1])
//   [65536, 196608): region2, npr in [0,128) (np = npr+64): pack(W_hh[g][2npr], [2npr+1])
__global__ void prep_weights(const float* __restrict__ We, const float* __restrict__ W_ih,
                             const float* __restrict__ W_hh, uint32* __restrict__ We2,
                             uint32* __restrict__ Wc2) {
    int idx = blockIdx.x * 256 + threadIdx.x;
    if (idx < 32768) {
        int p = idx & 3, s = (idx >> 2) & 127, jq = idx >> 9;
        int j = 8 * jq + 2 * p;
        We2[idx] = pack_f16(We[s * 512 + j], We[s * 512 + j + 1]);
    } else if (idx < 98304) {
        int i2 = idx - 32768;  // [0, 65536)
        int np = i2 >> 10, g = i2 & 1023;
        Wc2[i2] = pack_f16(W_ih[g * 128 + 2 * np], W_ih[g * 128 + 2 * np + 1]);
    } else if (idx < 229376) {
        int i3 = idx - 98304;  // [0, 131072)
        int p = i3 & 3, q = (i3 >> 2) & 255, npr = i3 >> 10;  // npr in [0,128)
        int g = 4 * q + p;
        int n0 = 2 * npr;
        Wc2[65536 + i3] = pack_f16(W_hh[g * 256 + n0], W_hh[g * 256 + n0 + 1]);
    }
}

// ---------- prep 2: Ux[b,s,n] = sum_t x[b,t,n] * Ue[s,t]  (bf16 out) ----------
__global__ void ux_kernel(const float* __restrict__ x, const float* __restrict__ Ue,
                          unsigned short* __restrict__ Uxg) {
    int b = blockIdx.x >> 1, h = blockIdx.x & 1;
    int n = threadIdx.x & 127, sg = threadIdx.x >> 7;
    int s0 = h * 64 + sg * 16;
    float acc[16];
#pragma unroll
    for (int k = 0; k < 16; ++k) acc[k] = 0.f;
    for (int t0 = 0; t0 < 128; t0 += 16) {
        float xv[16];
#pragma unroll
        for (int tt = 0; tt < 16; ++tt) xv[tt] = x[(b * 128 + t0 + tt) * 128 + n];
#pragma unroll
        for (int k = 0; k < 16; ++k) {
            const float4* uep = (const float4*)(Ue + (s0 + k) * 128 + t0);
            float4 u0 = uep[0], u1 = uep[1], u2 = uep[2], u3 = uep[3];
            acc[k] += xv[0] * u0.x + xv[1] * u0.y + xv[2] * u0.z + xv[3] * u0.w
                    + xv[4] * u1.x + xv[5] * u1.y + xv[6] * u1.z + xv[7] * u1.w
                    + xv[8] * u2.x + xv[9] * u2.y + xv[10] * u2.z + xv[11] * u2.w
                    + xv[12] * u3.x + xv[13] * u3.y + xv[14] * u3.z + xv[15] * u3.w;
        }
    }
#pragma unroll
    for (int k = 0; k < 16; ++k)
        Uxg[b * 16384 + (s0 + k) * 128 + n] = f2bf(acc[k]);
}

// ---------- main: 128 blocks, wave-specialized, barrier-free step loop ----------
// r1-verified protocol + register-resident weight slices (budget forced by
// amdgpu_waves_per_eu(4,4) -> 128 VGPR with exactly 16 waves/CU resident):
//   every thread owns gate gt = tid: wxr[32] = xw np[0,32), wh[32] = h np[64,96).
//   Streams: g0-3 h np[96,192) (384 KB/step), g4/5 ph1 then xw np[32,64) (128 KB).
//   cnt4 = 16 adds/step: 8 (g0-3) + 4 (g4/5) + 4 (B) — every vh_s h-pair READER
//   counts in before ph5 may overwrite vh_s (fixes r3's latent race).
__global__ __launch_bounds__(NT)
__attribute__((amdgpu_waves_per_eu(4, 4)))
void encoder_kernel(const float* __restrict__ x, const float* __restrict__ v_e,
                    const float* __restrict__ b_ih, const float* __restrict__ b_hh,
                    const unsigned short* __restrict__ Uxg, const uint4* __restrict__ We2q,
                    const uint4* __restrict__ Wc2q, float* __restrict__ out) {
    __shared__ __align__(16) unsigned short Ux_s[16384];  // 32 KB [s][n] bf16
    __shared__ __align__(16) float part4[6144];           // 24 KB [grp0..5][1024 gates]
    __shared__ float rxh_s[768];                          // reg-dot partials, gates 0..768
    __shared__ float part1[256];                          // [jg][s]
    __shared__ float part2[256];                          // [sg][n]
    __shared__ __align__(16) uint32 vh_s[192];   // half2 pairs of v=[xw-e(0..64)|h(64..192)]
    __shared__ __align__(16) uint32 hsh_s[256];  // half2 pairs of hs=[h(0..128)|c(128..256)]
    __shared__ float c_s[256];                   // f32 c state
    __shared__ __align__(16) float bias_s[1024];
    __shared__ uint32 xw_flag, cnt1, cnt2, cnt4, cnt5;

    const int tid = threadIdx.x;
    const int b = blockIdx.x;
    const uint32* Wc2u = (const uint32*)Wc2q;

    {   // load this batch's Ux tile (coalesced)
        const uint4* src = (const uint4*)(Uxg + b * 16384);
        uint4* dst = (uint4*)Ux_s;
        for (int i = tid; i < 2048; i += NT) dst[i] = src[i];
    }
    bias_s[tid] = b_ih[tid] + b_hh[tid];
    if (tid < 192) vh_s[tid] = 0u;
    if (tid < 256) { hsh_s[tid] = 0u; c_s[tid] = 0.f; }
    if (tid == 0) { xw_flag = 0; cnt1 = 0; cnt2 = 0; cnt4 = 0; cnt5 = 0; }
    // per-thread t-invariant weight registers for own gate gt = tid (64 VGPRs)
    uint32 wxr[32], wh[32];
#pragma unroll
    for (int i = 0; i < 32; ++i) wxr[i] = Wc2u[i * 1024 + tid];          // xw np [0,32)
#pragma unroll
    for (int i = 0; i < 32; ++i) wh[i] = Wc2u[65536 + i * 1024 + tid];   // h np [64,96)
    __syncthreads();  // the only barrier; all threads reach it

// own-gate register GEMVs: 8 broadcast ds_read_b128 + 32 fdot2 each
#define REG_H(dst)                                               \
    {                                                            \
        float r0 = 0.f, r1 = 0.f, r2 = 0.f, r3 = 0.f;            \
        _Pragma("unroll")                                        \
        for (int q = 0; q < 8; ++q) {                            \
            uint4 v4 = *(const uint4*)&vh_s[64 + 4 * q];         \
            r0 = fdot2(wh[4 * q + 0], v4.x, r0);                 \
            r1 = fdot2(wh[4 * q + 1], v4.y, r1);                 \
            r2 = fdot2(wh[4 * q + 2], v4.z, r2);                 \
            r3 = fdot2(wh[4 * q + 3], v4.w, r3);                 \
        }                                                        \
        dst = (r0 + r1) + (r2 + r3);                             \
    }
#define REG_X(dst)                                               \
    {                                                            \
        float r0 = 0.f, r1 = 0.f, r2 = 0.f, r3 = 0.f;            \
        _Pragma("unroll")                                        \
        for (int q = 0; q < 8; ++q) {                            \
            uint4 v4 = *(const uint4*)&vh_s[4 * q];              \
            r0 = fdot2(wxr[4 * q + 0], v4.x, r0);                \
            r1 = fdot2(wxr[4 * q + 1], v4.y, r1);                \
            r2 = fdot2(wxr[4 * q + 2], v4.z, r2);                \
            r3 = fdot2(wxr[4 * q + 3], v4.w, r3);                \
        }                                                        \
        dst = (r0 + r1) + (r2 + r3);                             \
    }

// 4-np stream block: 1 ds_read_b128 of v-pairs + 8 b128 weight loads + 32 fdot2
// wbase: uint4* base of the region; npr: np index within region; vnp: vh_s index
#define NP_BLOCK(wbase, npr, vnp)                                    \
    {                                                                \
        uint4 vp4 = *(const uint4*)&vh_s[(vnp)];                     \
        _Pragma("unroll")                                            \
        for (int u = 0; u < 4; ++u) {                                \
            uint32 vp = (&vp4.x)[u];                                 \
            const uint4* wp = (wbase) + ((npr) + u) * 256 + 2 * ol;  \
            uint4 w0 = wp[0], w1 = wp[1];                            \
            a0 = fdot2(w0.x, vp, a0); a1 = fdot2(w0.y, vp, a1);      \
            a2 = fdot2(w0.z, vp, a2); a3 = fdot2(w0.w, vp, a3);      \
            a4 = fdot2(w1.x, vp, a4); a5 = fdot2(w1.y, vp, a5);      \
            a6 = fdot2(w1.z, vp, a6); a7 = fdot2(w1.w, vp, a7);      \
        }                                                            \
    }

    if (tid < 768) {
        // ================= A-group =================
        const int ol = tid & 127, g = tid >> 7;
        float my_rh, my_rx;
        if (g < 4) {
            // -------- h streamers: np [96,192) in 4 groups of 24 --------
            const uint4* hw = Wc2q + 16384;        // region2 (npr = np-64)
            const int nb = 32 + 24 * g;            // npr base: [32,128) coverage
            for (int t = 0; t < 128; ++t) {
                spin_ge<4>(&cnt5, (uint32)(4 * t));
                float a0 = 0.f, a1 = 0.f, a2 = 0.f, a3 = 0.f;
                float a4 = 0.f, a5 = 0.f, a6 = 0.f, a7 = 0.f;
#pragma unroll 2
                for (int i = 0; i < 6; ++i) NP_BLOCK(hw, nb + 4 * i, 64 + nb + 4 * i);
                float4* p4 = (float4*)&part4[g * 1024 + 8 * ol];
                p4[0] = make_float4(a0, a1, a2, a3);
                p4[1] = make_float4(a4, a5, a6, a7);
                REG_H(my_rh);                       // vh h-pairs stable until cnt4 full
                spin_ge<1>(&xw_flag, (uint32)(t + 1));
                REG_X(my_rx);
                rxh_s[tid] = my_rh + my_rx;
                if ((tid & 63) == 0) add_flag(&cnt4, 1);
            }
        } else {
            // -------- ph1 waves (chain head) + xw tail stream np [32,64) --------
            __builtin_amdgcn_s_setprio(1);
            const int s = ol, jg = g - 4, jq0 = jg * 32;
            const int xb = 32 + 16 * jg;           // region1 npr base
            for (int t = 0; t < 128; ++t) {
                spin_ge<1>(&cnt5, (uint32)(4 * t));
                float c0 = 0.f, c1 = 0.f, c2 = 0.f, c3 = 0.f;
#pragma unroll 4
                for (int jq = jq0; jq < jq0 + 32; ++jq) {
                    uint4 w = We2q[jq * 128 + s];
                    uint4 hh = *(const uint4*)&hsh_s[4 * jq];
                    c0 = fdot2(w.x, hh.x, c0);
                    c1 = fdot2(w.y, hh.y, c1);
                    c2 = fdot2(w.z, hh.z, c2);
                    c3 = fdot2(w.w, hh.w, c3);
                }
                part1[jg * 128 + s] = (c0 + c1) + (c2 + c3);
                if ((tid & 63) == 0) add_flag(&cnt1, 1);
                REG_H(my_rh);
                spin_ge<1>(&xw_flag, (uint32)(t + 1));
                float a0 = 0.f, a1 = 0.f, a2 = 0.f, a3 = 0.f;
                float a4 = 0.f, a5 = 0.f, a6 = 0.f, a7 = 0.f;
#pragma unroll
                for (int i = 0; i < 4; ++i) NP_BLOCK(Wc2q, xb + 4 * i, xb + 4 * i);
                float4* p4 = (float4*)&part4[(4 + jg) * 1024 + 8 * ol];
                p4[0] = make_float4(a0, a1, a2, a3);
                p4[1] = make_float4(a4, a5, a6, a7);
                REG_X(my_rx);
                rxh_s[tid] = my_rh + my_rx;
                if ((tid & 63) == 0) add_flag(&cnt4, 1);
            }
        }
    } else {
        // ================= B-group =================
        __builtin_amdgcn_s_setprio(2);  // B is on the chain almost always
        const int bt = tid - 768, l = tid & 63;
        const int n = bt & 127, sg = bt >> 7;
        const float ve_lane = v_e[sg * 64 + l];  // lane l holds ve[sg*64+l]
        const unsigned short* uxrow = Ux_s + sg * 64 * 128 + n;
        const int j = bt;
        const float bi0 = bias_s[j], bf0 = bias_s[256 + j];
        const float bg0 = bias_s[512 + j], bo0 = bias_s[768 + j];
        float my_rh, my_rx;
        for (int t = 0; t < 128; ++t) {
            float2 xt2;
            if (bt < 64) xt2 = *(const float2*)(x + (b * 128 + t) * 128 + 2 * l);
            spin_ge<1>(&cnt1, (uint32)(4 * (t + 1)));
            // per-wave redundant web: lane l holds web[l], web[64+l]
            float web_lo = part1[l] + part1[128 + l];
            float web_hi = part1[64 + l] + part1[192 + l];
            float wsel = sg ? web_hi : web_lo;
            // ph2: scores partial over s-chunk sg (readlane broadcast, 2 acc chains)
            float acc0 = 0.f, acc1 = 0.f;
#pragma unroll
            for (int k = 0; k < 64; k += 2) {
                float wv0 = rdlane(wsel, k), ve0 = rdlane(ve_lane, k);
                float wv1 = rdlane(wsel, k + 1), ve1 = rdlane(ve_lane, k + 1);
                acc0 = fmaf(ve0, fast_tanh(wv0 + bfu(uxrow[k * 128])), acc0);
                acc1 = fmaf(ve1, fast_tanh(wv1 + bfu(uxrow[(k + 1) * 128])), acc1);
            }
            part2[sg * 128 + n] = acc0 + acc1;
            if (l == 0) add_flag(&cnt2, 1);
            if (bt < 64) {
                // ph3: softmax + xw pack (wave 12); lane l owns n=2l, 2l+1
                spin_ge<1>(&cnt2, (uint32)(4 * (t + 1)));
                __builtin_amdgcn_s_setprio(3);
                float v0 = part2[2 * l] + part2[128 + 2 * l];
                float v1 = part2[2 * l + 1] + part2[129 + 2 * l];
                // |score| <= sum|ve| ~ 6 -> raw exp is overflow-safe
                float e0 = fexp2(v0 * 1.4426950408889634f);
                float e1 = fexp2(v1 * 1.4426950408889634f);
                float ssum = e0 + e1;
#pragma unroll
                for (int off = 32; off > 0; off >>= 1) ssum += __shfl_xor(ssum, off);
                float inv = frcp(ssum);
                vh_s[l] = pack_f16(xt2.x * e0 * inv, xt2.y * e1 * inv);
                if (bt == 0) st_flag(&xw_flag, (uint32)(t + 1));
                __builtin_amdgcn_s_setprio(2);
                REG_H(my_rh);
                REG_X(my_rx);
            } else {
                REG_H(my_rh);
                spin_ge<1>(&xw_flag, (uint32)(t + 1));
                REG_X(my_rx);
            }
            if (l == 0) add_flag(&cnt4, 1);  // B counted: vh h-pairs consumed
            // ph5: gate assembly + LSTM pointwise (thread = h-unit j; own gate = o)
            spin_ge<1>(&cnt4, (uint32)(16 * (t + 1)));
            float gi = bi0 + rxh_s[j]
                     + part4[j] + part4[1024 + j] + part4[2048 + j] + part4[3072 + j]
                     + part4[4096 + j] + part4[5120 + j];
            float gf = bf0 + rxh_s[256 + j]
                     + part4[256 + j] + part4[1280 + j] + part4[2304 + j] + part4[3328 + j]
                     + part4[4352 + j] + part4[5376 + j];
            float gg = bg0 + rxh_s[512 + j]
                     + part4[512 + j] + part4[1536 + j] + part4[2560 + j] + part4[3584 + j]
                     + part4[4608 + j] + part4[5632 + j];
            float go = bo0 + (my_rh + my_rx)
                     + part4[768 + j] + part4[1792 + j] + part4[2816 + j] + part4[3840 + j]
                     + part4[4864 + j] + part4[5888 + j];
            float c = c_s[j];
            float c2v = fast_sigmoid(gf) * c + fast_sigmoid(gi) * fast_tanh(gg);
            float h2v = fast_sigmoid(go) * fast_tanh(c2v);
            c_s[j] = c2v;
            float hn = __shfl_xor(h2v, 1);
            float cn = __shfl_xor(c2v, 1);
            if (!(j & 1)) {
                uint32 hp = pack_f16(h2v, hn);
                vh_s[64 + (j >> 1)] = hp;                  // h-pairs for all GEMVs
                hsh_s[j >> 1] = hp;                        // hs h-pairs for ph1
                hsh_s[128 + (j >> 1)] = pack_f16(c2v, cn); // hs c-pairs
            }
            if (l == 0) add_flag(&cnt5, 1);
            // global store AFTER the release: keep its vmcnt off the handoff path
            out[(t * 128 + b) * 256 + j] = h2v;
        }
    }
#undef NP_BLOCK
#undef REG_H
#undef REG_X
}

extern "C" void kernel_launch(void* const* d_in, const int* in_sizes, int n_in,
                              void* d_out, int out_size, void* d_ws, size_t ws_size,
                              hipStream_t stream) {
    const float* x    = (const float*)d_in[0];
    const float* We   = (const float*)d_in[1];
    const float* Ue   = (const float*)d_in[2];
    const float* v_e  = (const float*)d_in[3];
    const float* W_ih = (const float*)d_in[4];
    const float* W_hh = (const float*)d_in[5];
    const float* b_ih = (const float*)d_in[6];
    const float* b_hh = (const float*)d_in[7];
    float* out = (float*)d_out;

    char* w = (char*)d_ws;
    unsigned short* Uxg = (unsigned short*)w;      // 4 MB
    uint32* We2 = (uint32*)(w + 4194304);          // 128 KB
    uint32* Wc2 = (uint32*)(w + 4325376);          // 768 KB (region1 xw | region2 h)

    prep_weights<<<896, 256, 0, stream>>>(We, W_ih, W_hh, We2, Wc2);
    ux_kernel<<<256, 512, 0, stream>>>(x, Ue, Uxg);
    encoder_kernel<<<128, NT, 0, stream>>>(x, v_e, b_ih, b_hh, Uxg,
                                           (const uint4*)We2, (const uint4*)Wc2, out);
}

// Round 7
// 3948.537 us; speedup vs baseline: 1.0729x; 1.0729x over previous
//
#include <hip/hip_runtime.h>
#include <hip/hip_bf16.h>
#include <hip/hip_fp16.h>

typedef unsigned int uint32;
typedef _Float16 hf2 __attribute__((ext_vector_type(2)));

#define NT 1024

// ---------- helpers ----------
__device__ __forceinline__ float bfu(unsigned short v) { return __uint_as_float(((uint32)v) << 16); }
__device__ __forceinline__ unsigned short f2bf(float f) {
    uint32 u = __float_as_uint(f);
    u = (u + 0x7fffu + ((u >> 16) & 1u)) >> 16;
    return (unsigned short)u;
}
__device__ __forceinline__ uint32 pack_f16(float a, float b) {
    __half ha = __float2half_rn(a), hb = __float2half_rn(b);
    return (uint32)__half_as_ushort(ha) | ((uint32)__half_as_ushort(hb) << 16);
}
__device__ __forceinline__ float fexp2(float x) {
#if __has_builtin(__builtin_amdgcn_exp2f)
    return __builtin_amdgcn_exp2f(x);
#else
    return exp2f(x);
#endif
}
__device__ __forceinline__ float frcp(float x) {
#if __has_builtin(__builtin_amdgcn_rcpf)
    return __builtin_amdgcn_rcpf(x);
#else
    return __fdividef(1.f, x);
#endif
}
// tanh = 1 - 2/(1+e^{2x}); saturates correctly, no clamp needed.
__device__ __forceinline__ float fast_tanh(float x) {
    float e = fexp2(x * 2.8853900817779268f);  // 2*log2(e)
    return fmaf(-2.f, frcp(1.f + e), 1.f);
}
__device__ __forceinline__ float fast_sigmoid(float x) {
    return frcp(1.f + fexp2(-1.4426950408889634f * x));
}
// broadcast lane k's value (k wave-uniform) without DS traffic
__device__ __forceinline__ float rdlane(float v, int k) {
#if __has_builtin(__builtin_amdgcn_readlane)
    return __builtin_bit_cast(float, __builtin_amdgcn_readlane(__builtin_bit_cast(int, v), k));
#else
    return __shfl(v, k);
#endif
}
// 2-way f16 dot with f32 accumulate (v_dot2_f32_f16), guarded fallback
__device__ __forceinline__ float fdot2(uint32 w, uint32 v, float acc) {
#if __has_builtin(__builtin_amdgcn_fdot2)
    return __builtin_amdgcn_fdot2(__builtin_bit_cast(hf2, w), __builtin_bit_cast(hf2, v), acc, false);
#else
    __half2 wh = __builtin_bit_cast(__half2, w), vh = __builtin_bit_cast(__half2, v);
    float2 wf = __half22float2(wh), vf = __half22float2(vh);
    return fmaf(wf.y, vf.y, fmaf(wf.x, vf.x, acc));
#endif
}

// LDS flag ops (workgroup scope); fast-path check before first sleep.
// Guard 1<<18: legit waits are <25k cycles; a broken wait costs ~10ms not minutes.
template <int S>
__device__ __forceinline__ void spin_ge(uint32* p, uint32 tgt) {
    if (__hip_atomic_load(p, __ATOMIC_ACQUIRE, __HIP_MEMORY_SCOPE_WORKGROUP) >= tgt) return;
    int guard = 0;
    do {
        __builtin_amdgcn_s_sleep(S);
        if (++guard > (1 << 18)) break;  // safety valve: wrong answer beats a hang
    } while (__hip_atomic_load(p, __ATOMIC_ACQUIRE, __HIP_MEMORY_SCOPE_WORKGROUP) < tgt);
}
// device-scope (cross-block) flag spin
template <int S>
__device__ __forceinline__ void spin_ge_g(const uint32* p, uint32 tgt) {
    if (__hip_atomic_load(p, __ATOMIC_ACQUIRE, __HIP_MEMORY_SCOPE_AGENT) >= tgt) return;
    int guard = 0;
    do {
        __builtin_amdgcn_s_sleep(S);
        if (++guard > (1 << 18)) break;
    } while (__hip_atomic_load(p, __ATOMIC_ACQUIRE, __HIP_MEMORY_SCOPE_AGENT) < tgt);
}
__device__ __forceinline__ void st_flag(uint32* p, uint32 v) {
    __hip_atomic_store(p, v, __ATOMIC_RELEASE, __HIP_MEMORY_SCOPE_WORKGROUP);
}
__device__ __forceinline__ void add_flag(uint32* p, uint32 v) {
    __hip_atomic_fetch_add(p, v, __ATOMIC_RELEASE, __HIP_MEMORY_SCOPE_WORKGROUP);
}

// ---------- prep 1: f16-convert + re-layout weights ----------
// We2: uint4[64][128]; [jq][s] = 4 half2 of We rows (hs reduction j in [0,512))
// Wc2: uint32 [np in 0..192)][gc in 0..1024): half-permuted gate columns.
//   gc = H*512 + q*128 + j  (H = block half, q = gate type i/f/g/o, j = local unit)
//   global gate g = q*256 + H*128 + j
//   np<64: xw pair (W_ih cols 2np,2np+1); np>=64: h pair (W_hh cols 2(np-64),+1)
// Also zeroes the 256 cross-block flags.
__global__ void prep_weights(const float* __restrict__ We, const float* __restrict__ W_ih,
                             const float* __restrict__ W_hh, uint32* __restrict__ We2,
                             uint32* __restrict__ Wc2, uint32* __restrict__ gflag) {
    int idx = blockIdx.x * 256 + threadIdx.x;
    if (idx < 32768) {
        int p = idx & 3, s = (idx >> 2) & 127, jq = idx >> 9;
        int j = 8 * jq + 2 * p;
        We2[idx] = pack_f16(We[s * 512 + j], We[s * 512 + j + 1]);
    } else if (idx < 229376) {
        int i2 = idx - 32768;               // [0, 196608)
        int np = i2 >> 10, gc = i2 & 1023;  // np in [0,192)
        int Hh = gc >> 9, q = (gc >> 7) & 3, j = gc & 127;
        int g = q * 256 + Hh * 128 + j;
        float w0, w1;
        if (np < 64) {
            w0 = W_ih[g * 128 + 2 * np];
            w1 = W_ih[g * 128 + 2 * np + 1];
        } else {
            int nn = 2 * (np - 64);
            w0 = W_hh[g * 256 + nn];
            w1 = W_hh[g * 256 + nn + 1];
        }
        Wc2[i2] = pack_f16(w0, w1);
    } else if (idx < 229632) {
        gflag[idx - 229376] = 0;
    }
}

// ---------- prep 2: Ux[b,s,n] = sum_t x[b,t,n] * Ue[s,t]  (bf16 out) ----------
__global__ void ux_kernel(const float* __restrict__ x, const float* __restrict__ Ue,
                          unsigned short* __restrict__ Uxg) {
    int b = blockIdx.x >> 1, h = blockIdx.x & 1;
    int n = threadIdx.x & 127, sg = threadIdx.x >> 7;
    int s0 = h * 64 + sg * 16;
    float acc[16];
#pragma unroll
    for (int k = 0; k < 16; ++k) acc[k] = 0.f;
    for (int t0 = 0; t0 < 128; t0 += 16) {
        float xv[16];
#pragma unroll
        for (int tt = 0; tt < 16; ++tt) xv[tt] = x[(b * 128 + t0 + tt) * 128 + n];
#pragma unroll
        for (int k = 0; k < 16; ++k) {
            const float4* uep = (const float4*)(Ue + (s0 + k) * 128 + t0);
            float4 u0 = uep[0], u1 = uep[1], u2 = uep[2], u3 = uep[3];
            acc[k] += xv[0] * u0.x + xv[1] * u0.y + xv[2] * u0.z + xv[3] * u0.w
                    + xv[4] * u1.x + xv[5] * u1.y + xv[6] * u1.z + xv[7] * u1.w
                    + xv[8] * u2.x + xv[9] * u2.y + xv[10] * u2.z + xv[11] * u2.w
                    + xv[12] * u3.x + xv[13] * u3.y + xv[14] * u3.z + xv[15] * u3.w;
        }
    }
#pragma unroll
    for (int k = 0; k < 16; ++k)
        Uxg[b * 16384 + (s0 + k) * 128 + n] = f2bf(acc[k]);
}

// ---------- main: 256 blocks (2 per batch), COOPERATIVE launch ----------
// Block bid: batch = bid&127, half H = bid>>7, partner = bid^128. Cooperative
// launch guarantees all 256 blocks co-resident (1 block/CU via LDS pad).
// Per block: 512 gates (H's i/f/g/o of units H*128..+128). Attention replicated.
//   waves 0-7  (tid<512):  h-part stream np[64+16a,+16) then xw stream np[8a,+8)
//   waves 8-11 (tid<768):  ph1 (We·hs, full 512 reduction)
//   waves 12-15 (B):       ph2 all; w12 ph3; w12/13 ph5 (128 units) + publish h/c
//                          to global + agent release; w14/15 acquire partner h/c
//                          -> LDS. cnt5 = 4/step: 2 ph5 + 2 loader. cnt4 = 12.
__global__ __launch_bounds__(NT, 4)
void encoder_kernel(const float* __restrict__ x, const float* __restrict__ v_e,
                    const float* __restrict__ b_ih, const float* __restrict__ b_hh,
                    const unsigned short* __restrict__ Uxg, const uint4* __restrict__ We2q,
                    const uint4* __restrict__ Wc2q, uint32* __restrict__ gflag,
                    uint32* __restrict__ xd, float* __restrict__ out) {
    __shared__ __align__(16) unsigned short Ux_s[16384];  // 32 KB [s][n] bf16
    __shared__ __align__(16) float part4[4096];           // 16 KB [wave0..7][512 gates]
    __shared__ float part1[256];                          // [jg][s]
    __shared__ float part2[256];                          // [sg][n]
    __shared__ __align__(16) uint32 vh_s[192];   // half2 pairs v=[xw-e(0..64)|h(64..192)]
    __shared__ __align__(16) uint32 hsh_s[256];  // half2 pairs hs=[h(0..128)|c(128..256)]
    __shared__ float c_s[128];                   // f32 c state (local units)
    __shared__ __align__(16) float bias_s[512];  // [gl] = b_ih+b_hh of our gates
    __shared__ uint32 xw_flag, cnt1, cnt2, cnt4, cnt5;
    __shared__ float pad_force[8192];  // 32 KB pad -> LDS>80KB -> 1 block/CU

    const int tid = threadIdx.x;
    const int bid = blockIdx.x;
    const int batch = bid & 127, H = bid >> 7, PH = 1 - H;
    const int partner = bid ^ 128;
    uint32* xdst = xd + bid * 128;
    const uint32* xsrc = xd + partner * 128;

    {   // load this batch's Ux tile (coalesced)
        const uint4* src = (const uint4*)(Uxg + batch * 16384);
        uint4* dst = (uint4*)Ux_s;
        for (int i = tid; i < 2048; i += NT) dst[i] = src[i];
    }
    if (tid < 512) {  // bias for our 512 gates, gl = q*128 + j
        int q = tid >> 7, j = tid & 127;
        int g = q * 256 + H * 128 + j;
        bias_s[tid] = b_ih[g] + b_hh[g];
    }
    if (tid < 192) vh_s[tid] = 0u;
    if (tid < 256) hsh_s[tid] = 0u;
    if (tid < 128) c_s[tid] = 0.f;
    if (tid == 0) { xw_flag = 0; cnt1 = 0; cnt2 = 0; cnt4 = 0; cnt5 = 0; }
    __syncthreads();  // the only barrier; all threads reach it

// 4-np stream block: 1 ds_read_b128 of v-pairs + 8 b128 weight loads + 32 fdot2
// wb = Wc2q + H*128 + 2*ol (per-thread base); vh index == np
#define NP_BLOCK(npb)                                                \
    {                                                                \
        uint4 vp4 = *(const uint4*)&vh_s[(npb)];                     \
        _Pragma("unroll")                                            \
        for (int u = 0; u < 4; ++u) {                                \
            uint32 vp = (&vp4.x)[u];                                 \
            const uint4* wp = wb + ((npb) + u) * 256;                \
            uint4 w0 = wp[0], w1 = wp[1];                            \
            a0 = fdot2(w0.x, vp, a0); a1 = fdot2(w0.y, vp, a1);      \
            a2 = fdot2(w0.z, vp, a2); a3 = fdot2(w0.w, vp, a3);      \
            a4 = fdot2(w1.x, vp, a4); a5 = fdot2(w1.y, vp, a5);      \
            a6 = fdot2(w1.z, vp, a6); a7 = fdot2(w1.w, vp, a7);      \
        }                                                            \
    }

    if (tid < 512) {
        // ================= h/xw stream waves (8) =================
        const int a = tid >> 6, ol = tid & 63;  // gates 8ol..8ol+7 (local gl)
        const uint4* wb = Wc2q + H * 128 + 2 * ol;
        const int hnp0 = 64 + 16 * a;  // h np range [hnp0, hnp0+16)
        const int xnp0 = 8 * a;        // xw np range [xnp0, xnp0+8)
        for (int t = 0; t < 128; ++t) {
            spin_ge<4>(&cnt5, (uint32)(4 * t));
            float a0 = 0.f, a1 = 0.f, a2 = 0.f, a3 = 0.f;
            float a4 = 0.f, a5 = 0.f, a6 = 0.f, a7 = 0.f;
#pragma unroll
            for (int i = 0; i < 4; ++i) NP_BLOCK(hnp0 + 4 * i);
            spin_ge<1>(&xw_flag, (uint32)(t + 1));
#pragma unroll
            for (int i = 0; i < 2; ++i) NP_BLOCK(xnp0 + 4 * i);
            float4* p4 = (float4*)&part4[a * 512 + 8 * ol];
            p4[0] = make_float4(a0, a1, a2, a3);
            p4[1] = make_float4(a4, a5, a6, a7);
            if (ol == 0) add_flag(&cnt4, 1);
        }
    } else if (tid < 768) {
        // ================= ph1 waves (4, chain head) =================
        __builtin_amdgcn_s_setprio(1);
        const int k = (tid >> 6) - 8, lane = tid & 63;
        const int s = (k & 1) * 64 + lane, jg = k >> 1, jq0 = jg * 32;
        for (int t = 0; t < 128; ++t) {
            spin_ge<1>(&cnt5, (uint32)(4 * t));
            float c0 = 0.f, c1 = 0.f, c2 = 0.f, c3 = 0.f;
#pragma unroll 4
            for (int jq = jq0; jq < jq0 + 32; ++jq) {
                uint4 w = We2q[jq * 128 + s];
                uint4 hh = *(const uint4*)&hsh_s[4 * jq];
                c0 = fdot2(w.x, hh.x, c0);
                c1 = fdot2(w.y, hh.y, c1);
                c2 = fdot2(w.z, hh.z, c2);
                c3 = fdot2(w.w, hh.w, c3);
            }
            part1[jg * 128 + s] = (c0 + c1) + (c2 + c3);
            if (lane == 0) { add_flag(&cnt1, 1); add_flag(&cnt4, 1); }
        }
    } else {
        // ================= B-group (4 waves) =================
        __builtin_amdgcn_s_setprio(2);
        const int bt = tid - 768, l = tid & 63;
        const int n = bt & 127, sg = bt >> 7;
        const float ve_lane = v_e[sg * 64 + l];
        const unsigned short* uxrow = Ux_s + sg * 64 * 128 + n;
        for (int t = 0; t < 128; ++t) {
            float2 xt2;
            if (bt < 64) xt2 = *(const float2*)(x + (batch * 128 + t) * 128 + 2 * l);
            spin_ge<1>(&cnt1, (uint32)(4 * (t + 1)));
            // per-wave redundant web: lane l holds web[l], web[64+l]
            float web_lo = part1[l] + part1[128 + l];
            float web_hi = part1[64 + l] + part1[192 + l];
            float wsel = sg ? web_hi : web_lo;
            // ph2: scores partial over s-chunk sg
            float acc0 = 0.f, acc1 = 0.f;
#pragma unroll
            for (int k = 0; k < 64; k += 2) {
                float wv0 = rdlane(wsel, k), ve0 = rdlane(ve_lane, k);
                float wv1 = rdlane(wsel, k + 1), ve1 = rdlane(ve_lane, k + 1);
                acc0 = fmaf(ve0, fast_tanh(wv0 + bfu(uxrow[k * 128])), acc0);
                acc1 = fmaf(ve1, fast_tanh(wv1 + bfu(uxrow[(k + 1) * 128])), acc1);
            }
            part2[sg * 128 + n] = acc0 + acc1;
            if (l == 0) add_flag(&cnt2, 1);
            if (bt < 64) {
                // ph3: softmax + xw pack (wave 12); lane l owns n=2l, 2l+1
                spin_ge<1>(&cnt2, (uint32)(4 * (t + 1)));
                __builtin_amdgcn_s_setprio(3);
                float v0 = part2[2 * l] + part2[128 + 2 * l];
                float v1 = part2[2 * l + 1] + part2[129 + 2 * l];
                // |score| <= sum|ve| ~ 6 -> raw exp is overflow-safe
                float e0 = fexp2(v0 * 1.4426950408889634f);
                float e1 = fexp2(v1 * 1.4426950408889634f);
                float ssum = e0 + e1;
#pragma unroll
                for (int off = 32; off > 0; off >>= 1) ssum += __shfl_xor(ssum, off);
                float inv = frcp(ssum);
                vh_s[l] = pack_f16(xt2.x * e0 * inv, xt2.y * e1 * inv);
                if (bt == 0) st_flag(&xw_flag, (uint32)(t + 1));
                __builtin_amdgcn_s_setprio(2);
            }
            if (bt < 128) {
                // ph5: gate assembly + pointwise for local unit j = bt
                spin_ge<1>(&cnt4, (uint32)(12 * (t + 1)));
                const int j = bt;
                float gi = bias_s[j], gf = bias_s[128 + j];
                float gg = bias_s[256 + j], go = bias_s[384 + j];
#pragma unroll
                for (int a = 0; a < 8; ++a) {
                    const float* pp = part4 + a * 512;
                    gi += pp[j]; gf += pp[128 + j];
                    gg += pp[256 + j]; go += pp[384 + j];
                }
                float c = c_s[j];
                float c2v = fast_sigmoid(gf) * c + fast_sigmoid(gi) * fast_tanh(gg);
                float h2v = fast_sigmoid(go) * fast_tanh(c2v);
                c_s[j] = c2v;
                float hn = __shfl_xor(h2v, 1);
                float cn = __shfl_xor(c2v, 1);
                if (!(j & 1)) {
                    uint32 hp = pack_f16(h2v, hn);
                    uint32 cp = pack_f16(c2v, cn);
                    int p = H * 64 + (j >> 1);  // global pair index
                    vh_s[64 + p] = hp;          // h-pairs for GEMVs
                    hsh_s[p] = hp;              // hs h-pairs for ph1
                    hsh_s[128 + p] = cp;        // hs c-pairs
                    xdst[j >> 1] = hp;          // publish to partner
                    xdst[64 + (j >> 1)] = cp;
                }
                if (l == 0) {
                    // release: orders this wave's global stores before the flag
                    __hip_atomic_fetch_add(gflag + bid, 1, __ATOMIC_RELEASE,
                                           __HIP_MEMORY_SCOPE_AGENT);
                    add_flag(&cnt5, 1);
                }
                out[(t * 128 + batch) * 256 + H * 128 + j] = h2v;
            } else {
                // partner-loader: pull partner's h/c pairs into LDS
                const int wv = bt - 128;  // [0,128)
                spin_ge<1>(&cnt4, (uint32)(12 * (t + 1)));
                spin_ge_g<1>(gflag + partner, (uint32)(2 * (t + 1)));
                uint32 v = xsrc[wv];
                if (wv < 64) {
                    vh_s[64 + PH * 64 + wv] = v;
                    hsh_s[PH * 64 + wv] = v;
                } else {
                    hsh_s[128 + PH * 64 + (wv - 64)] = v;
                }
                if (l == 0) add_flag(&cnt5, 1);
            }
        }
        // keep pad_force alive (never true at runtime)
        if (__hip_atomic_load(&cnt5, __ATOMIC_RELAXED, __HIP_MEMORY_SCOPE_WORKGROUP) == 0xffffffffu)
            pad_force[tid] = 0.f;
    }
#undef NP_BLOCK
}

extern "C" void kernel_launch(void* const* d_in, const int* in_sizes, int n_in,
                              void* d_out, int out_size, void* d_ws, size_t ws_size,
                              hipStream_t stream) {
    const float* x    = (const float*)d_in[0];
    const float* We   = (const float*)d_in[1];
    const float* Ue   = (const float*)d_in[2];
    const float* v_e  = (const float*)d_in[3];
    const float* W_ih = (const float*)d_in[4];
    const float* W_hh = (const float*)d_in[5];
    const float* b_ih = (const float*)d_in[6];
    const float* b_hh = (const float*)d_in[7];
    float* out = (float*)d_out;

    char* w = (char*)d_ws;
    unsigned short* Uxg = (unsigned short*)w;      // 4 MB
    uint32* We2 = (uint32*)(w + 4194304);          // 128 KB
    uint32* Wc2 = (uint32*)(w + 4325376);          // 768 KB half-permuted
    uint32* gflag = (uint32*)(w + 5111808);        // 1 KB cross-block flags
    uint32* xd = (uint32*)(w + 5112832);           // 128 KB h/c exchange

    prep_weights<<<897, 256, 0, stream>>>(We, W_ih, W_hh, We2, Wc2, gflag);
    ux_kernel<<<256, 512, 0, stream>>>(x, Ue, Uxg);

    // cooperative launch: co-residency of all 256 blocks is GUARANTEED, which
    // the pair-exchange protocol requires. Fallback: plain launch (empty GPU,
    // 1 block/CU -> co-resident in practice) if cooperative path errors.
    const unsigned short* Uxg_c = Uxg;
    const uint4* We2_c = (const uint4*)We2;
    const uint4* Wc2_c = (const uint4*)Wc2;
    uint32* gflag_c = gflag;
    uint32* xd_c = xd;
    void* kargs[] = {(void*)&x, (void*)&v_e, (void*)&b_ih, (void*)&b_hh,
                     (void*)&Uxg_c, (void*)&We2_c, (void*)&Wc2_c,
                     (void*)&gflag_c, (void*)&xd_c, (void*)&out};
    hipError_t err = hipLaunchCooperativeKernel((const void*)encoder_kernel,
                                                dim3(256), dim3(NT), kargs, 0, stream);
    if (err != hipSuccess) {
        encoder_kernel<<<256, NT, 0, stream>>>(x, v_e, b_ih, b_hh, Uxg,
                                               (const uint4*)We2, (const uint4*)Wc2,
                                               gflag, xd, out);
    }
}

// Round 8
// 1259.770 us; speedup vs baseline: 3.3627x; 3.1343x over previous
//
#include <hip/hip_runtime.h>
#include <hip/hip_bf16.h>
#include <hip/hip_fp16.h>

typedef unsigned int uint32;
typedef _Float16 hf2 __attribute__((ext_vector_type(2)));

#define NT 1024

// ---------- helpers ----------
__device__ __forceinline__ float bfu(unsigned short v) { return __uint_as_float(((uint32)v) << 16); }
__device__ __forceinline__ unsigned short f2bf(float f) {
    uint32 u = __float_as_uint(f);
    u = (u + 0x7fffu + ((u >> 16) & 1u)) >> 16;
    return (unsigned short)u;
}
__device__ __forceinline__ uint32 pack_f16(float a, float b) {
    __half ha = __float2half_rn(a), hb = __float2half_rn(b);
    return (uint32)__half_as_ushort(ha) | ((uint32)__half_as_ushort(hb) << 16);
}
__device__ __forceinline__ float fexp2(float x) {
#if __has_builtin(__builtin_amdgcn_exp2f)
    return __builtin_amdgcn_exp2f(x);
#else
    return exp2f(x);
#endif
}
__device__ __forceinline__ float frcp(float x) {
#if __has_builtin(__builtin_amdgcn_rcpf)
    return __builtin_amdgcn_rcpf(x);
#else
    return __fdividef(1.f, x);
#endif
}
// tanh = 1 - 2/(1+e^{2x}); saturates correctly, no clamp needed.
__device__ __forceinline__ float fast_tanh(float x) {
    float e = fexp2(x * 2.8853900817779268f);  // 2*log2(e)
    return fmaf(-2.f, frcp(1.f + e), 1.f);
}
__device__ __forceinline__ float fast_sigmoid(float x) {
    return frcp(1.f + fexp2(-1.4426950408889634f * x));
}
// broadcast lane k's value (k wave-uniform) without DS traffic
__device__ __forceinline__ float rdlane(float v, int k) {
#if __has_builtin(__builtin_amdgcn_readlane)
    return __builtin_bit_cast(float, __builtin_amdgcn_readlane(__builtin_bit_cast(int, v), k));
#else
    return __shfl(v, k);
#endif
}
// 2-way f16 dot with f32 accumulate (v_dot2_f32_f16), guarded fallback
__device__ __forceinline__ float fdot2(uint32 w, uint32 v, float acc) {
#if __has_builtin(__builtin_amdgcn_fdot2)
    return __builtin_amdgcn_fdot2(__builtin_bit_cast(hf2, w), __builtin_bit_cast(hf2, v), acc, false);
#else
    __half2 wh = __builtin_bit_cast(__half2, w), vh = __builtin_bit_cast(__half2, v);
    float2 wf = __half22float2(wh), vf = __half22float2(vh);
    return fmaf(wf.y, vf.y, fmaf(wf.x, vf.x, acc));
#endif
}

// LDS flag ops (workgroup scope); fast-path check before first sleep
template <int S>
__device__ __forceinline__ void spin_ge(uint32* p, uint32 tgt) {
    if (__hip_atomic_load(p, __ATOMIC_ACQUIRE, __HIP_MEMORY_SCOPE_WORKGROUP) >= tgt) return;
    int guard = 0;
    do {
        __builtin_amdgcn_s_sleep(S);
        if (++guard > (1 << 22)) break;  // safety valve: wrong answer beats a hang
    } while (__hip_atomic_load(p, __ATOMIC_ACQUIRE, __HIP_MEMORY_SCOPE_WORKGROUP) < tgt);
}
__device__ __forceinline__ void st_flag(uint32* p, uint32 v) {
    __hip_atomic_store(p, v, __ATOMIC_RELEASE, __HIP_MEMORY_SCOPE_WORKGROUP);
}
__device__ __forceinline__ void add_flag(uint32* p, uint32 v) {
    __hip_atomic_fetch_add(p, v, __ATOMIC_RELEASE, __HIP_MEMORY_SCOPE_WORKGROUP);
}

// ---------- prep 1: f16-convert + re-layout weights (r1 layout, proven) ----------
// We2: uint4[64][128]; [jq][s] = 4 half2 of We rows (hs reduction j in [0,512))
// Wc2: uint4[192][256]; [np][q] = 4 half2: gate g=4q+p gets (W[g][2np], W[g][2np+1])
//      K-dim n in [0,384) = [xw(128)|h(256)]
__global__ void prep_weights(const float* __restrict__ We, const float* __restrict__ W_ih,
                             const float* __restrict__ W_hh, uint32* __restrict__ We2,
                             uint32* __restrict__ Wc2) {
    int idx = blockIdx.x * 256 + threadIdx.x;
    if (idx < 32768) {
        int p = idx & 3, s = (idx >> 2) & 127, jq = idx >> 9;
        int j = 8 * jq + 2 * p;
        We2[idx] = pack_f16(We[s * 512 + j], We[s * 512 + j + 1]);
    } else if (idx < 229376) {
        int i2 = idx - 32768;
        int p = i2 & 3, q = (i2 >> 2) & 255, np = i2 >> 10;
        int g = 4 * q + p;
        int n0 = 2 * np, n1 = 2 * np + 1;
        float w0, w1;
        if (n0 < 128) {
            w0 = W_ih[g * 128 + n0];
            w1 = W_ih[g * 128 + n1];
        } else {
            w0 = W_hh[g * 256 + (n0 - 128)];
            w1 = W_hh[g * 256 + (n1 - 128)];
        }
        Wc2[i2] = pack_f16(w0, w1);
    }
}

// ---------- prep 2: Ux[b,s,n] = sum_t x[b,t,n] * Ue[s,t]  (bf16 out) ----------
__global__ void ux_kernel(const float* __restrict__ x, const float* __restrict__ Ue,
                          unsigned short* __restrict__ Uxg) {
    int b = blockIdx.x >> 1, h = blockIdx.x & 1;
    int n = threadIdx.x & 127, sg = threadIdx.x >> 7;
    int s0 = h * 64 + sg * 16;
    float acc[16];
#pragma unroll
    for (int k = 0; k < 16; ++k) acc[k] = 0.f;
    for (int t0 = 0; t0 < 128; t0 += 16) {
        float xv[16];
#pragma unroll
        for (int tt = 0; tt < 16; ++tt) xv[tt] = x[(b * 128 + t0 + tt) * 128 + n];
#pragma unroll
        for (int k = 0; k < 16; ++k) {
            const float4* uep = (const float4*)(Ue + (s0 + k) * 128 + t0);
            float4 u0 = uep[0], u1 = uep[1], u2 = uep[2], u3 = uep[3];
            acc[k] += xv[0] * u0.x + xv[1] * u0.y + xv[2] * u0.z + xv[3] * u0.w
                    + xv[4] * u1.x + xv[5] * u1.y + xv[6] * u1.z + xv[7] * u1.w
                    + xv[8] * u2.x + xv[9] * u2.y + xv[10] * u2.z + xv[11] * u2.w
                    + xv[12] * u3.x + xv[13] * u3.y + xv[14] * u3.z + xv[15] * u3.w;
        }
    }
#pragma unroll
    for (int k = 0; k < 16; ++k)
        Uxg[b * 16384 + (s0 + k) * 128 + n] = f2bf(acc[k]);
}

// ---------- main: 128 blocks, wave-specialized, barrier-free step loop ----------
// EXACT r1 protocol (1332us verified): A g0-3 h-stream np[64+32g,+32); g4/5 ph1
// then xw-stream np[32jg,+32); B ph2 -> w12 ph3 -> ph5. Flags: cnt1(4), cnt2(4),
// cnt4(12, A only), cnt5(4), xw_flag. NEW: We2 jq[0,48) staged in LDS (96 KB) so
// the chain-head ph1 no longer contends with the h-stream for the L2 port;
// bias held in B-thread registers (frees the 4 KB that makes the staging fit).
__global__ __launch_bounds__(NT, 4)
void encoder_kernel(const float* __restrict__ x, const float* __restrict__ v_e,
                    const float* __restrict__ b_ih, const float* __restrict__ b_hh,
                    const unsigned short* __restrict__ Uxg, const uint4* __restrict__ We2q,
                    const uint4* __restrict__ Wc2q, float* __restrict__ out) {
    __shared__ __align__(16) unsigned short Ux_s[16384];  // 32 KB [s][n] bf16
    __shared__ __align__(16) uint4 We2L[6144];            // 96 KB We2 jq[0,48)
    __shared__ __align__(16) float part4[6144];           // 24 KB [grp][1024 gates]
    __shared__ float part1[256];                          // [jg][s]
    __shared__ float part2[256];                          // [sg][n]
    __shared__ __align__(16) uint32 vh_s[192];   // half2 pairs of v=[xw(0..64)|h(64..192)]
    __shared__ __align__(16) uint32 hsh_s[256];  // half2 pairs of hs=[h(0..128)|c(128..256)]
    __shared__ float c_s[256];                   // f32 c state
    __shared__ uint32 xw_flag, cnt1, cnt2, cnt4, cnt5;

    const int tid = threadIdx.x;
    const int b = blockIdx.x;

    {   // load this batch's Ux tile (coalesced)
        const uint4* src = (const uint4*)(Uxg + b * 16384);
        uint4* dst = (uint4*)Ux_s;
        for (int i = tid; i < 2048; i += NT) dst[i] = src[i];
    }
    // stage We2 jq[0,48) in LDS (96 KB; chain-head reads become port-free)
    for (int i = tid; i < 6144; i += NT) We2L[i] = We2q[i];
    if (tid < 192) vh_s[tid] = 0u;
    if (tid < 256) { hsh_s[tid] = 0u; c_s[tid] = 0.f; }
    if (tid == 0) { xw_flag = 0; cnt1 = 0; cnt2 = 0; cnt4 = 0; cnt5 = 0; }
    // B-thread bias registers (replaces bias_s LDS; r2-proven)
    float bi0 = 0.f, bf0 = 0.f, bg0 = 0.f, bo0 = 0.f;
    if (tid >= 768) {
        int j = tid - 768;
        bi0 = b_ih[j] + b_hh[j];
        bf0 = b_ih[256 + j] + b_hh[256 + j];
        bg0 = b_ih[512 + j] + b_hh[512 + j];
        bo0 = b_ih[768 + j] + b_hh[768 + j];
    }
    __syncthreads();  // the only barrier; all threads reach it

// 4-np stream block: 1 ds_read_b128 of v-pairs + 8 b128 weight loads + 32 fdot2
#define NP_BLOCK(npb)                                                \
    {                                                                \
        uint4 vp4 = *(const uint4*)&vh_s[(npb)];                     \
        _Pragma("unroll")                                            \
        for (int u = 0; u < 4; ++u) {                                \
            uint32 vp = (&vp4.x)[u];                                 \
            const uint4* wp = wc + ((npb) + u) * 256;                \
            uint4 w0 = wp[0], w1 = wp[1];                            \
            a0 = fdot2(w0.x, vp, a0); a1 = fdot2(w0.y, vp, a1);      \
            a2 = fdot2(w0.z, vp, a2); a3 = fdot2(w0.w, vp, a3);      \
            a4 = fdot2(w1.x, vp, a4); a5 = fdot2(w1.y, vp, a5);      \
            a6 = fdot2(w1.z, vp, a6); a7 = fdot2(w1.w, vp, a7);      \
        }                                                            \
    }

    if (tid < 768) {
        // ================= A-group =================
        const int ol = tid & 127, g = tid >> 7;
        if (g >= 4) __builtin_amdgcn_s_setprio(1);  // ph1/xw are chain phases
        const uint4* wc = Wc2q + 2 * ol;
        for (int t = 0; t < 128; ++t) {
            float a0 = 0.f, a1 = 0.f, a2 = 0.f, a3 = 0.f;
            float a4 = 0.f, a5 = 0.f, a6 = 0.f, a7 = 0.f;
            if (g < 4) {
                // h-part has thousands of cycles of slack: cheap slow polls
                spin_ge<4>(&cnt5, (uint32)(4 * t));
                const int np0 = 64 + g * 32;
#pragma unroll 2
                for (int i = 0; i < 8; ++i) NP_BLOCK(np0 + 4 * i);
            } else {
                spin_ge<1>(&cnt5, (uint32)(4 * t));
                // ph1: web partial over hs-chunk jg; jq[0,48) LDS, jq[48,64) L2
                const int s = ol, jg = g - 4;
                float acc = 0.f;
                if (jg == 0) {
#pragma unroll 4
                    for (int jq = 0; jq < 32; ++jq) {
                        uint4 w = We2L[jq * 128 + s];
                        uint4 hh = *(const uint4*)&hsh_s[4 * jq];
                        acc = fdot2(w.x, hh.x, acc);
                        acc = fdot2(w.y, hh.y, acc);
                        acc = fdot2(w.z, hh.z, acc);
                        acc = fdot2(w.w, hh.w, acc);
                    }
                } else {
#pragma unroll 4
                    for (int jq = 32; jq < 48; ++jq) {
                        uint4 w = We2L[jq * 128 + s];
                        uint4 hh = *(const uint4*)&hsh_s[4 * jq];
                        acc = fdot2(w.x, hh.x, acc);
                        acc = fdot2(w.y, hh.y, acc);
                        acc = fdot2(w.z, hh.z, acc);
                        acc = fdot2(w.w, hh.w, acc);
                    }
#pragma unroll 4
                    for (int jq = 48; jq < 64; ++jq) {
                        uint4 w = We2q[jq * 128 + s];
                        uint4 hh = *(const uint4*)&hsh_s[4 * jq];
                        acc = fdot2(w.x, hh.x, acc);
                        acc = fdot2(w.y, hh.y, acc);
                        acc = fdot2(w.z, hh.z, acc);
                        acc = fdot2(w.w, hh.w, acc);
                    }
                }
                part1[jg * 128 + s] = acc;
                if ((tid & 63) == 0) add_flag(&cnt1, 1);
                // xw-part: np in [32(g-4), 32(g-4)+32) -- chain tail, fast wake
                spin_ge<1>(&xw_flag, (uint32)(t + 1));
                const int np0 = jg * 32;
#pragma unroll 2
                for (int i = 0; i < 8; ++i) NP_BLOCK(np0 + 4 * i);
            }
            float4* p4 = (float4*)&part4[g * 1024 + 8 * ol];
            p4[0] = make_float4(a0, a1, a2, a3);
            p4[1] = make_float4(a4, a5, a6, a7);
            if ((tid & 63) == 0) add_flag(&cnt4, 1);
        }
    } else {
        // ================= B-group =================
        __builtin_amdgcn_s_setprio(2);  // B is on the chain almost always
        const int bt = tid - 768, l = tid & 63;
        const int n = bt & 127, sg = bt >> 7;
        const float ve_lane = v_e[sg * 64 + l];  // lane l holds ve[sg*64+l]
        const unsigned short* uxrow = Ux_s + sg * 64 * 128 + n;
        for (int t = 0; t < 128; ++t) {
            float2 xt2;
            if (bt < 64) xt2 = *(const float2*)(x + (b * 128 + t) * 128 + 2 * l);
            spin_ge<1>(&cnt1, (uint32)(4 * (t + 1)));
            // per-wave redundant web: lane l holds web[l], web[64+l]
            float web_lo = part1[l] + part1[128 + l];
            float web_hi = part1[64 + l] + part1[192 + l];
            float wsel = sg ? web_hi : web_lo;
            // ph2: scores partial over s-chunk sg (readlane broadcast, 2 acc chains)
            float acc0 = 0.f, acc1 = 0.f;
#pragma unroll
            for (int k = 0; k < 64; k += 2) {
                float wv0 = rdlane(wsel, k), ve0 = rdlane(ve_lane, k);
                float wv1 = rdlane(wsel, k + 1), ve1 = rdlane(ve_lane, k + 1);
                acc0 = fmaf(ve0, fast_tanh(wv0 + bfu(uxrow[k * 128])), acc0);
                acc1 = fmaf(ve1, fast_tanh(wv1 + bfu(uxrow[(k + 1) * 128])), acc1);
            }
            part2[sg * 128 + n] = acc0 + acc1;
            if (l == 0) add_flag(&cnt2, 1);
            if (bt < 64) {
                // ph3: softmax + xw pack (wave 12); lane l owns n=2l, 2l+1
                spin_ge<1>(&cnt2, (uint32)(4 * (t + 1)));
                __builtin_amdgcn_s_setprio(3);
                float v0 = part2[2 * l] + part2[128 + 2 * l];
                float v1 = part2[2 * l + 1] + part2[129 + 2 * l];
                // |score| <= sum|ve| ~ 6 -> raw exp is overflow-safe
                float e0 = fexp2(v0 * 1.4426950408889634f);
                float e1 = fexp2(v1 * 1.4426950408889634f);
                float ssum = e0 + e1;
#pragma unroll
                for (int off = 32; off > 0; off >>= 1) ssum += __shfl_xor(ssum, off);
                float inv = frcp(ssum);
                vh_s[l] = pack_f16(xt2.x * e0 * inv, xt2.y * e1 * inv);
                if (bt == 0) st_flag(&xw_flag, (uint32)(t + 1));
                __builtin_amdgcn_s_setprio(2);
            }
            // ph5: gate reduce + LSTM pointwise (all 4 B-waves; thread = h-unit j)
            spin_ge<1>(&cnt4, (uint32)(12 * (t + 1)));
            const int j = bt;
            float gi = bi0, gf = bf0, gg = bg0, go = bo0;
#pragma unroll
            for (int gr = 0; gr < 6; ++gr) {
                const float* pp = part4 + gr * 1024;
                gi += pp[j]; gf += pp[256 + j];
                gg += pp[512 + j]; go += pp[768 + j];
            }
            float c = c_s[j];
            float c2 = fast_sigmoid(gf) * c + fast_sigmoid(gi) * fast_tanh(gg);
            float h2v = fast_sigmoid(go) * fast_tanh(c2);
            c_s[j] = c2;
            float hn = __shfl_xor(h2v, 1);
            float cn = __shfl_xor(c2, 1);
            if (!(j & 1)) {
                uint32 hp = pack_f16(h2v, hn);
                vh_s[64 + (j >> 1)] = hp;       // v h-pairs for gate GEMV
                hsh_s[j >> 1] = hp;             // hs h-pairs for ph1
                hsh_s[128 + (j >> 1)] = pack_f16(c2, cn);  // hs c-pairs
            }
            if (l == 0) add_flag(&cnt5, 1);     // A-waves spin on cnt5 directly
            // global store AFTER the release: keep its vmcnt off the handoff path
            out[(t * 128 + b) * 256 + j] = h2v;
        }
    }
#undef NP_BLOCK
}

extern "C" void kernel_launch(void* const* d_in, const int* in_sizes, int n_in,
                              void* d_out, int out_size, void* d_ws, size_t ws_size,
                              hipStream_t stream) {
    const float* x    = (const float*)d_in[0];
    const float* We   = (const float*)d_in[1];
    const float* Ue   = (const float*)d_in[2];
    const float* v_e  = (const float*)d_in[3];
    const float* W_ih = (const float*)d_in[4];
    const float* W_hh = (const float*)d_in[5];
    const float* b_ih = (const float*)d_in[6];
    const float* b_hh = (const float*)d_in[7];
    float* out = (float*)d_out;

    char* w = (char*)d_ws;
    unsigned short* Uxg = (unsigned short*)w;      // 4 MB
    uint32* We2 = (uint32*)(w + 4194304);          // 128 KB
    uint32* Wc2 = (uint32*)(w + 4325376);          // 768 KB

    prep_weights<<<896, 256, 0, stream>>>(We, W_ih, W_hh, We2, Wc2);
    ux_kernel<<<256, 512, 0, stream>>>(x, Ue, Uxg);
    encoder_kernel<<<128, NT, 0, stream>>>(x, v_e, b_ih, b_hh, Uxg,
                                           (const uint4*)We2, (const uint4*)Wc2, out);
}

// Round 9
// 1056.305 us; speedup vs baseline: 4.0105x; 1.1926x over previous
//
#include <hip/hip_runtime.h>
#include <hip/hip_bf16.h>
#include <hip/hip_fp16.h>

typedef unsigned int uint32;
typedef _Float16 hf2 __attribute__((ext_vector_type(2)));

#define NT 1024

// ---------- helpers ----------
__device__ __forceinline__ float bfu(unsigned short v) { return __uint_as_float(((uint32)v) << 16); }
__device__ __forceinline__ unsigned short f2bf(float f) {
    uint32 u = __float_as_uint(f);
    u = (u + 0x7fffu + ((u >> 16) & 1u)) >> 16;
    return (unsigned short)u;
}
__device__ __forceinline__ uint32 pack_f16(float a, float b) {
    __half ha = __float2half_rn(a), hb = __float2half_rn(b);
    return (uint32)__half_as_ushort(ha) | ((uint32)__half_as_ushort(hb) << 16);
}
__device__ __forceinline__ float fexp2(float x) {
#if __has_builtin(__builtin_amdgcn_exp2f)
    return __builtin_amdgcn_exp2f(x);
#else
    return exp2f(x);
#endif
}
__device__ __forceinline__ float frcp(float x) {
#if __has_builtin(__builtin_amdgcn_rcpf)
    return __builtin_amdgcn_rcpf(x);
#else
    return __fdividef(1.f, x);
#endif
}
// tanh = 1 - 2/(1+e^{2x}); saturates correctly, no clamp needed.
__device__ __forceinline__ float fast_tanh(float x) {
    float e = fexp2(x * 2.8853900817779268f);  // 2*log2(e)
    return fmaf(-2.f, frcp(1.f + e), 1.f);
}
__device__ __forceinline__ float fast_sigmoid(float x) {
    return frcp(1.f + fexp2(-1.4426950408889634f * x));
}
// broadcast lane k's value (k wave-uniform) without DS traffic
__device__ __forceinline__ float rdlane(float v, int k) {
#if __has_builtin(__builtin_amdgcn_readlane)
    return __builtin_bit_cast(float, __builtin_amdgcn_readlane(__builtin_bit_cast(int, v), k));
#else
    return __shfl(v, k);
#endif
}
// 2-way f16 dot with f32 accumulate (v_dot2_f32_f16), guarded fallback
__device__ __forceinline__ float fdot2(uint32 w, uint32 v, float acc) {
#if __has_builtin(__builtin_amdgcn_fdot2)
    return __builtin_amdgcn_fdot2(__builtin_bit_cast(hf2, w), __builtin_bit_cast(hf2, v), acc, false);
#else
    __half2 wh = __builtin_bit_cast(__half2, w), vh = __builtin_bit_cast(__half2, v);
    float2 wf = __half22float2(wh), vf = __half22float2(vh);
    return fmaf(wf.y, vf.y, fmaf(wf.x, vf.x, acc));
#endif
}

// LDS flag ops (workgroup scope)
// sleep variant: for slack-rich waves (poll cost matters less than issue slots)
template <int S>
__device__ __forceinline__ void spin_ge(uint32* p, uint32 tgt) {
    if (__hip_atomic_load(p, __ATOMIC_ACQUIRE, __HIP_MEMORY_SCOPE_WORKGROUP) >= tgt) return;
    int guard = 0;
    do {
        __builtin_amdgcn_s_sleep(S);
        if (++guard > (1 << 22)) break;  // safety valve: wrong answer beats a hang
    } while (__hip_atomic_load(p, __ATOMIC_ACQUIRE, __HIP_MEMORY_SCOPE_WORKGROUP) < tgt);
}
// busy variant: for chain-critical wakes — no sleep quantization (~64-256cy saved)
__device__ __forceinline__ void spin_busy(uint32* p, uint32 tgt) {
    int guard = 0;
    while (__hip_atomic_load(p, __ATOMIC_ACQUIRE, __HIP_MEMORY_SCOPE_WORKGROUP) < tgt) {
        if (++guard > (1 << 24)) break;  // safety valve
    }
}
__device__ __forceinline__ void st_flag(uint32* p, uint32 v) {
    __hip_atomic_store(p, v, __ATOMIC_RELEASE, __HIP_MEMORY_SCOPE_WORKGROUP);
}
__device__ __forceinline__ void add_flag(uint32* p, uint32 v) {
    __hip_atomic_fetch_add(p, v, __ATOMIC_RELEASE, __HIP_MEMORY_SCOPE_WORKGROUP);
}

// ---------- prep 1: f16-convert + re-layout weights (r1 layout, proven) ----------
// We2: uint4[64][128]; [jq][s] = 4 half2 of We rows (hs reduction j in [0,512))
// Wc2: uint4[192][256]; [np][q] = 4 half2: gate g=4q+p gets (W[g][2np], W[g][2np+1])
//      K-dim n in [0,384) = [xw(128)|h(256)]
__global__ void prep_weights(const float* __restrict__ We, const float* __restrict__ W_ih,
                             const float* __restrict__ W_hh, uint32* __restrict__ We2,
                             uint32* __restrict__ Wc2) {
    int idx = blockIdx.x * 256 + threadIdx.x;
    if (idx < 32768) {
        int p = idx & 3, s = (idx >> 2) & 127, jq = idx >> 9;
        int j = 8 * jq + 2 * p;
        We2[idx] = pack_f16(We[s * 512 + j], We[s * 512 + j + 1]);
    } else if (idx < 229376) {
        int i2 = idx - 32768;
        int p = i2 & 3, q = (i2 >> 2) & 255, np = i2 >> 10;
        int g = 4 * q + p;
        int n0 = 2 * np, n1 = 2 * np + 1;
        float w0, w1;
        if (n0 < 128) {
            w0 = W_ih[g * 128 + n0];
            w1 = W_ih[g * 128 + n1];
        } else {
            w0 = W_hh[g * 256 + (n0 - 128)];
            w1 = W_hh[g * 256 + (n1 - 128)];
        }
        Wc2[i2] = pack_f16(w0, w1);
    }
}

// ---------- prep 2: Ux[b,s,n] = sum_t x[b,t,n] * Ue[s,t]  (bf16 out) ----------
__global__ void ux_kernel(const float* __restrict__ x, const float* __restrict__ Ue,
                          unsigned short* __restrict__ Uxg) {
    int b = blockIdx.x >> 1, h = blockIdx.x & 1;
    int n = threadIdx.x & 127, sg = threadIdx.x >> 7;
    int s0 = h * 64 + sg * 16;
    float acc[16];
#pragma unroll
    for (int k = 0; k < 16; ++k) acc[k] = 0.f;
    for (int t0 = 0; t0 < 128; t0 += 16) {
        float xv[16];
#pragma unroll
        for (int tt = 0; tt < 16; ++tt) xv[tt] = x[(b * 128 + t0 + tt) * 128 + n];
#pragma unroll
        for (int k = 0; k < 16; ++k) {
            const float4* uep = (const float4*)(Ue + (s0 + k) * 128 + t0);
            float4 u0 = uep[0], u1 = uep[1], u2 = uep[2], u3 = uep[3];
            acc[k] += xv[0] * u0.x + xv[1] * u0.y + xv[2] * u0.z + xv[3] * u0.w
                    + xv[4] * u1.x + xv[5] * u1.y + xv[6] * u1.z + xv[7] * u1.w
                    + xv[8] * u2.x + xv[9] * u2.y + xv[10] * u2.z + xv[11] * u2.w
                    + xv[12] * u3.x + xv[13] * u3.y + xv[14] * u3.z + xv[15] * u3.w;
        }
    }
#pragma unroll
    for (int k = 0; k < 16; ++k)
        Uxg[b * 16384 + (s0 + k) * 128 + n] = f2bf(acc[k]);
}

// ---------- main: 128 blocks, wave-specialized, barrier-free step loop ----------
// r8 structure (1225us verified: 96KB We2 LDS staging) + 3 chain cuts:
//   (1) defer-norm softmax: xw_flag released before sum-reduce; 1/sum -> inv_s;
//       ph5 scales the xw partials (part4 slots 4/5 are pure xw). cnt4 = 13.
//   (2) ph1 L2 slice balanced: each jg reads 24 LDS-jq + 8 L2-jq (L2 issued first).
//   (3) busy-wait (no s_sleep) on chain-critical spins; g0-3 keep sleep(4).
__global__ __launch_bounds__(NT, 4)
void encoder_kernel(const float* __restrict__ x, const float* __restrict__ v_e,
                    const float* __restrict__ b_ih, const float* __restrict__ b_hh,
                    const unsigned short* __restrict__ Uxg, const uint4* __restrict__ We2q,
                    const uint4* __restrict__ Wc2q, float* __restrict__ out) {
    __shared__ __align__(16) unsigned short Ux_s[16384];  // 32 KB [s][n] bf16
    __shared__ __align__(16) uint4 We2L[6144];            // 96 KB We2 jq[0,48)
    __shared__ __align__(16) float part4[6144];           // 24 KB [grp][1024 gates]
    __shared__ float part1[256];                          // [jg][s]
    __shared__ float part2[256];                          // [sg][n]
    __shared__ __align__(16) uint32 vh_s[192];   // half2 pairs of v=[x*e(0..64)|h(64..192)]
    __shared__ __align__(16) uint32 hsh_s[256];  // half2 pairs of hs=[h(0..128)|c(128..256)]
    __shared__ float c_s[256];                   // f32 c state
    __shared__ float inv_s;                      // 1/sum(e) for current step
    __shared__ uint32 xw_flag, cnt1, cnt2, cnt4, cnt5;

    const int tid = threadIdx.x;
    const int b = blockIdx.x;

    {   // load this batch's Ux tile (coalesced)
        const uint4* src = (const uint4*)(Uxg + b * 16384);
        uint4* dst = (uint4*)Ux_s;
        for (int i = tid; i < 2048; i += NT) dst[i] = src[i];
    }
    // stage We2 jq[0,48) in LDS (96 KB; chain-head reads become port-free)
    for (int i = tid; i < 6144; i += NT) We2L[i] = We2q[i];
    if (tid < 192) vh_s[tid] = 0u;
    if (tid < 256) { hsh_s[tid] = 0u; c_s[tid] = 0.f; }
    if (tid == 0) { xw_flag = 0; cnt1 = 0; cnt2 = 0; cnt4 = 0; cnt5 = 0; inv_s = 0.f; }
    // B-thread bias registers (replaces bias_s LDS)
    float bi0 = 0.f, bf0 = 0.f, bg0 = 0.f, bo0 = 0.f;
    if (tid >= 768) {
        int j = tid - 768;
        bi0 = b_ih[j] + b_hh[j];
        bf0 = b_ih[256 + j] + b_hh[256 + j];
        bg0 = b_ih[512 + j] + b_hh[512 + j];
        bo0 = b_ih[768 + j] + b_hh[768 + j];
    }
    __syncthreads();  // the only barrier; all threads reach it

// 4-np stream block: 1 ds_read_b128 of v-pairs + 8 b128 weight loads + 32 fdot2
#define NP_BLOCK(npb)                                                \
    {                                                                \
        uint4 vp4 = *(const uint4*)&vh_s[(npb)];                     \
        _Pragma("unroll")                                            \
        for (int u = 0; u < 4; ++u) {                                \
            uint32 vp = (&vp4.x)[u];                                 \
            const uint4* wp = wc + ((npb) + u) * 256;                \
            uint4 w0 = wp[0], w1 = wp[1];                            \
            a0 = fdot2(w0.x, vp, a0); a1 = fdot2(w0.y, vp, a1);      \
            a2 = fdot2(w0.z, vp, a2); a3 = fdot2(w0.w, vp, a3);      \
            a4 = fdot2(w1.x, vp, a4); a5 = fdot2(w1.y, vp, a5);      \
            a6 = fdot2(w1.z, vp, a6); a7 = fdot2(w1.w, vp, a7);      \
        }                                                            \
    }

    if (tid < 768) {
        // ================= A-group =================
        const int ol = tid & 127, g = tid >> 7;
        if (g >= 4) __builtin_amdgcn_s_setprio(1);  // ph1/xw are chain phases
        const uint4* wc = Wc2q + 2 * ol;
        for (int t = 0; t < 128; ++t) {
            float a0 = 0.f, a1 = 0.f, a2 = 0.f, a3 = 0.f;
            float a4 = 0.f, a5 = 0.f, a6 = 0.f, a7 = 0.f;
            if (g < 4) {
                // h-part has thousands of cycles of slack: cheap slow polls
                spin_ge<4>(&cnt5, (uint32)(4 * t));
                const int np0 = 64 + g * 32;
#pragma unroll 2
                for (int i = 0; i < 8; ++i) NP_BLOCK(np0 + 4 * i);
            } else {
                spin_busy(&cnt5, (uint32)(4 * t));
                // ph1: web partial; balanced split: 8 L2 jq (issued first) + 24 LDS jq
                const int s = ol, jg = g - 4;
                const int lq0 = jg * 24;      // LDS jq base: 0 or 24
                const int gq0 = 48 + jg * 8;  // L2 jq base: 48 or 56
                float acc = 0.f;
#pragma unroll
                for (int jq = gq0; jq < gq0 + 8; ++jq) {
                    uint4 w = We2q[jq * 128 + s];
                    uint4 hh = *(const uint4*)&hsh_s[4 * jq];
                    acc = fdot2(w.x, hh.x, acc);
                    acc = fdot2(w.y, hh.y, acc);
                    acc = fdot2(w.z, hh.z, acc);
                    acc = fdot2(w.w, hh.w, acc);
                }
#pragma unroll 4
                for (int jq = lq0; jq < lq0 + 24; ++jq) {
                    uint4 w = We2L[jq * 128 + s];
                    uint4 hh = *(const uint4*)&hsh_s[4 * jq];
                    acc = fdot2(w.x, hh.x, acc);
                    acc = fdot2(w.y, hh.y, acc);
                    acc = fdot2(w.z, hh.z, acc);
                    acc = fdot2(w.w, hh.w, acc);
                }
                part1[jg * 128 + s] = acc;
                if ((tid & 63) == 0) add_flag(&cnt1, 1);
                // xw-part: np in [32(g-4), 32(g-4)+32) -- chain tail, fast wake
                spin_busy(&xw_flag, (uint32)(t + 1));
                const int np0 = jg * 32;
#pragma unroll 2
                for (int i = 0; i < 8; ++i) NP_BLOCK(np0 + 4 * i);
            }
            float4* p4 = (float4*)&part4[g * 1024 + 8 * ol];
            p4[0] = make_float4(a0, a1, a2, a3);
            p4[1] = make_float4(a4, a5, a6, a7);
            if ((tid & 63) == 0) add_flag(&cnt4, 1);
        }
    } else {
        // ================= B-group =================
        __builtin_amdgcn_s_setprio(2);  // B is on the chain almost always
        const int bt = tid - 768, l = tid & 63;
        const int n = bt & 127, sg = bt >> 7;
        const float ve_lane = v_e[sg * 64 + l];  // lane l holds ve[sg*64+l]
        const unsigned short* uxrow = Ux_s + sg * 64 * 128 + n;
        for (int t = 0; t < 128; ++t) {
            float2 xt2;
            if (bt < 64) xt2 = *(const float2*)(x + (b * 128 + t) * 128 + 2 * l);
            spin_busy(&cnt1, (uint32)(4 * (t + 1)));
            // per-wave redundant web: lane l holds web[l], web[64+l]
            float web_lo = part1[l] + part1[128 + l];
            float web_hi = part1[64 + l] + part1[192 + l];
            float wsel = sg ? web_hi : web_lo;
            // ph2: scores partial over s-chunk sg (readlane broadcast, 2 acc chains)
            float acc0 = 0.f, acc1 = 0.f;
#pragma unroll
            for (int k = 0; k < 64; k += 2) {
                float wv0 = rdlane(wsel, k), ve0 = rdlane(ve_lane, k);
                float wv1 = rdlane(wsel, k + 1), ve1 = rdlane(ve_lane, k + 1);
                acc0 = fmaf(ve0, fast_tanh(wv0 + bfu(uxrow[k * 128])), acc0);
                acc1 = fmaf(ve1, fast_tanh(wv1 + bfu(uxrow[(k + 1) * 128])), acc1);
            }
            part2[sg * 128 + n] = acc0 + acc1;
            if (l == 0) add_flag(&cnt2, 1);
            if (bt < 64) {
                // ph3: biased-free exp + x*e pack; xw released BEFORE the reduce
                spin_busy(&cnt2, (uint32)(4 * (t + 1)));
                __builtin_amdgcn_s_setprio(3);
                float v0 = part2[2 * l] + part2[128 + 2 * l];
                float v1 = part2[2 * l + 1] + part2[129 + 2 * l];
                // |score| <= sum|ve| ~ 6 -> e <= ~300, x*e <= ~1500 fits f16
                float e0 = fexp2(v0 * 1.4426950408889634f);
                float e1 = fexp2(v1 * 1.4426950408889634f);
                vh_s[l] = pack_f16(xt2.x * e0, xt2.y * e1);  // UNNORMALIZED
                if (bt == 0) st_flag(&xw_flag, (uint32)(t + 1));
                __builtin_amdgcn_s_setprio(2);
                // off-chain: sum-reduce + inv; ph5 consumers gated via cnt4 (13th add)
                float ssum = e0 + e1;
#pragma unroll
                for (int off = 32; off > 0; off >>= 1) ssum += __shfl_xor(ssum, off);
                if (bt == 0) { inv_s = frcp(ssum); add_flag(&cnt4, 1); }
            }
            // ph5: gate reduce + LSTM pointwise (all 4 B-waves; thread = h-unit j)
            spin_busy(&cnt4, (uint32)(13 * (t + 1)));
            const float inv = inv_s;
            const int j = bt;
            // h partials (slots 0-3) plain; xw partials (slots 4-5) scaled by inv
            float gi = bi0 + part4[j] + part4[1024 + j] + part4[2048 + j] + part4[3072 + j]
                     + (part4[4096 + j] + part4[5120 + j]) * inv;
            float gf = bf0 + part4[256 + j] + part4[1280 + j] + part4[2304 + j] + part4[3328 + j]
                     + (part4[4352 + j] + part4[5376 + j]) * inv;
            float gg = bg0 + part4[512 + j] + part4[1536 + j] + part4[2560 + j] + part4[3584 + j]
                     + (part4[4608 + j] + part4[5632 + j]) * inv;
            float go = bo0 + part4[768 + j] + part4[1792 + j] + part4[2816 + j] + part4[3840 + j]
                     + (part4[4864 + j] + part4[5888 + j]) * inv;
            float c = c_s[j];
            float c2 = fast_sigmoid(gf) * c + fast_sigmoid(gi) * fast_tanh(gg);
            float h2v = fast_sigmoid(go) * fast_tanh(c2);
            c_s[j] = c2;
            float hn = __shfl_xor(h2v, 1);
            float cn = __shfl_xor(c2, 1);
            if (!(j & 1)) {
                uint32 hp = pack_f16(h2v, hn);
                vh_s[64 + (j >> 1)] = hp;       // v h-pairs for gate GEMV
                hsh_s[j >> 1] = hp;             // hs h-pairs for ph1
                hsh_s[128 + (j >> 1)] = pack_f16(c2, cn);  // hs c-pairs
            }
            if (l == 0) add_flag(&cnt5, 1);     // A-waves spin on cnt5 directly
            // global store AFTER the release: keep its vmcnt off the handoff path
            out[(t * 128 + b) * 256 + j] = h2v;
        }
    }
#undef NP_BLOCK
}

extern "C" void kernel_launch(void* const* d_in, const int* in_sizes, int n_in,
                              void* d_out, int out_size, void* d_ws, size_t ws_size,
                              hipStream_t stream) {
    const float* x    = (const float*)d_in[0];
    const float* We   = (const float*)d_in[1];
    const float* Ue   = (const float*)d_in[2];
    const float* v_e  = (const float*)d_in[3];
    const float* W_ih = (const float*)d_in[4];
    const float* W_hh = (const float*)d_in[5];
    const float* b_ih = (const float*)d_in[6];
    const float* b_hh = (const float*)d_in[7];
    float* out = (float*)d_out;

    char* w = (char*)d_ws;
    unsigned short* Uxg = (unsigned short*)w;      // 4 MB
    uint32* We2 = (uint32*)(w + 4194304);          // 128 KB
    uint32* Wc2 = (uint32*)(w + 4325376);          // 768 KB

    prep_weights<<<896, 256, 0, stream>>>(We, W_ih, W_hh, We2, Wc2);
    ux_kernel<<<256, 512, 0, stream>>>(x, Ue, Uxg);
    encoder_kernel<<<128, NT, 0, stream>>>(x, v_e, b_ih, b_hh, Uxg,
                                           (const uint4*)We2, (const uint4*)Wc2, out);
}